// Round 10
// baseline (94.148 us; speedup 1.0000x reference)
//
#include <hip/hip_runtime.h>

#define B_ 32
#define T_ 4096
#define D_ 256
#define A_ 128

typedef __attribute__((ext_vector_type(8))) short bf16x8;
typedef __attribute__((ext_vector_type(4))) float f32x4;
typedef __attribute__((address_space(3))) void lds_void_t;
typedef const __attribute__((address_space(1))) void gbl_void_t;

__device__ __forceinline__ ushort f32_to_bf16_rne(float x) {
    uint u = __float_as_uint(x);
    u = (u + 0x7FFFu + ((u >> 16) & 1u)) >> 16;
    return (ushort)u;
}
__device__ __forceinline__ float bf16_bits_to_f32(ushort b) {
    return __uint_as_float(((uint)b) << 16);
}

// fast tanh: 1 - 2/(e^{2x}+1); exp overflow -> +-1 naturally.
__device__ __forceinline__ float fast_tanh(float x) {
    float t = __expf(2.0f * x);
    float r = __builtin_amdgcn_rcpf(t + 1.0f);
    return fmaf(-2.0f, r, 1.0f);
}

// split 8 f32 -> hi bf16x8 (round-half-up) + lo bf16x8 (exact residual)
__device__ __forceinline__ void split8(float4 a, float4 b, bf16x8& hi8, bf16x8& lo8) {
    float xs[8] = {a.x, a.y, a.z, a.w, b.x, b.y, b.z, b.w};
    union { uint w[4]; bf16x8 v; } H, L;
#pragma unroll
    for (int p = 0; p < 4; ++p) {
        float x0 = xs[2 * p], x1 = xs[2 * p + 1];
        uint r0 = __float_as_uint(x0) + 0x8000u;
        uint r1 = __float_as_uint(x1) + 0x8000u;
        H.w[p] = __builtin_amdgcn_perm(r1, r0, 0x07060302u);
        float rem0 = x0 - __uint_as_float(r0 & 0xFFFF0000u);
        float rem1 = x1 - __uint_as_float(r1 & 0xFFFF0000u);
        L.w[p] = __builtin_amdgcn_perm(__float_as_uint(rem1), __float_as_uint(rem0), 0x07060302u);
    }
    hi8 = H.v;
    lo8 = L.v;
}

// -----------------------------------------------------------------------------
// Kernel 0: build the FULL pre-swizzled W LDS image (128 KB).
// Byte layout: plane(0=hi,1=lo)*65536 + row*512 + s'*16, where slot s' holds
// W[row][k = (s'^(row&7))*8 .. +8). A linear 128KB copy into LDS then gives
// the swizzled layout the MFMA loop reads (rule #21: swizzle folded in source).
// -----------------------------------------------------------------------------
__global__ __launch_bounds__(256) void convert_W_kernel(
    const float* __restrict__ W, ushort* __restrict__ Wimg)
{
    const int c  = blockIdx.x * 256 + threadIdx.x;  // 16B chunk id, 0..8191
    const int p  = c >> 12;                         // plane
    const int r  = (c >> 5) & 127;                  // row
    const int sp = c & 31;                          // swizzled slot
    const int s  = sp ^ (r & 7);                    // source slot
    const float* src = W + (size_t)r * D_ + s * 8;

    union { ushort us[8]; float4 v; } out;
#pragma unroll
    for (int i = 0; i < 8; ++i) {
        float x = src[i];
        ushort hb = f32_to_bf16_rne(x);
        out.us[i] = p ? f32_to_bf16_rne(x - bf16_bits_to_f32(hb)) : hb;
    }
    *reinterpret_cast<float4*>(Wimg + (size_t)c * 8) = out.v;
}

// -----------------------------------------------------------------------------
// Kernel 1 (fused): score (split-bf16 MFMA) + flash-local pool.
// FULL W image staged into LDS ONCE (128 KB via global_load_lds) -> the K-loop
// has ZERO barriers and no re-staging. Each wave streams its 16 rows with a
// depth-3 rolling h prefetch; the only vmcnt waits are the compiler's in-order
// consumption of the h stream, so younger prefetches always stay in flight.
// Block = 16 waves x 16 rows = 256 rows = one flash chunk; grid 512; 1 blk/CU.
// Pool re-reads the block's own 256 rows (L2/L3-hot; R9 proved full absorption).
// -----------------------------------------------------------------------------
__global__ __launch_bounds__(1024, 4) void score_pool_kernel(
    const float* __restrict__ h, const ushort* __restrict__ Wimg,
    const float* __restrict__ bw, const float* __restrict__ uw,
    float* __restrict__ part, float2* __restrict__ stats)
{
    __shared__ char wlds[131072];       // [plane][row][swizzled 16B slot]
    __shared__ float sc[256];
    __shared__ float elds[256];
    __shared__ float ssum[4];
    __shared__ float4 redp[16][64];

    const int tid  = threadIdx.x;
    const int w    = tid >> 6;          // 0..15
    const int lane = tid & 63;
    const int l15  = lane & 15;
    const int l4   = lane >> 4;
    const int rowbase = blockIdx.x * 256 + w * 16;

    // ---- stage the full W image (linear copy; swizzle already in source) ----
#pragma unroll
    for (int i = 0; i < 8; ++i) {
        __builtin_amdgcn_global_load_lds(
            (gbl_void_t*)((const char*)Wimg + i * 16384 + tid * 16),
            (lds_void_t*)(wlds + i * 16384 + tid * 16), 16, 0, 0);
    }

    const float* hrow = h + (size_t)(rowbase + l15) * D_ + l4 * 8;

    float4 hbuf[8][2];
#define PREF(s)                                                             \
    {                                                                       \
        hbuf[s][0] = *reinterpret_cast<const float4*>(hrow + (s) * 32);     \
        hbuf[s][1] = *reinterpret_cast<const float4*>(hrow + (s) * 32 + 4); \
    }
    PREF(0); PREF(1); PREF(2);

    __syncthreads();   // one-time drain: W image resident, h(0..2) landed

    f32x4 acc[8];
#pragma unroll
    for (int j = 0; j < 8; ++j)
#pragma unroll
        for (int r = 0; r < 4; ++r) acc[j][r] = 0.f;

    // ---- barrier-free K-loop ----
#pragma unroll
    for (int kk = 0; kk < 8; ++kk) {
        if (kk < 5) PREF(kk + 3);

        bf16x8 ahi, alo;
        split8(hbuf[kk][0], hbuf[kk][1], ahi, alo);

#pragma unroll
        for (int j = 0; j < 8; ++j) {
            const int row = j * 16 + l15;
            const int slot = kk * 4 + l4;
            const int off = row * 512 + ((slot ^ (row & 7)) << 4);
            bf16x8 wh = *reinterpret_cast<const bf16x8*>(wlds + off);
            bf16x8 wl = *reinterpret_cast<const bf16x8*>(wlds + 65536 + off);
            acc[j] = __builtin_amdgcn_mfma_f32_16x16x32_bf16(ahi, wh, acc[j], 0, 0, 0);
            acc[j] = __builtin_amdgcn_mfma_f32_16x16x32_bf16(alo, wh, acc[j], 0, 0, 0);
            acc[j] = __builtin_amdgcn_mfma_f32_16x16x32_bf16(ahi, wl, acc[j], 0, 0, 0);
        }
    }
#undef PREF

    // ---- scores for the wave's 16 rows ----
    float rsum[4] = {0.f, 0.f, 0.f, 0.f};
#pragma unroll
    for (int j = 0; j < 8; ++j) {
        const float bwv = bw[j * 16 + l15];
        const float uwv = uw[j * 16 + l15];
#pragma unroll
        for (int r = 0; r < 4; ++r)
            rsum[r] = fmaf(fast_tanh(acc[j][r] + bwv), uwv, rsum[r]);
    }
#pragma unroll
    for (int r = 0; r < 4; ++r) {
#pragma unroll
        for (int m = 1; m < 16; m <<= 1)
            rsum[r] += __shfl_xor(rsum[r], m, 64);
    }
    if (l15 == 0) {
#pragma unroll
        for (int r = 0; r < 4; ++r)
            sc[w * 16 + l4 * 4 + r] = rsum[r];
    }
    __syncthreads();

    // ---- flash-local softmax over the block's 256 rows ----
    float m_c = -3.0e38f;
#pragma unroll 32
    for (int t = 0; t < 256; ++t) m_c = fmaxf(m_c, sc[t]);   // LDS broadcast

    if (tid < 256) {
        float e = __expf(sc[tid] - m_c);
        elds[tid] = e;
        float s = e;
#pragma unroll
        for (int msk = 1; msk < 64; msk <<= 1) s += __shfl_xor(s, msk, 64);
        if ((tid & 63) == 0) ssum[tid >> 6] = s;
    }
    __syncthreads();
    if (tid == 0)
        stats[blockIdx.x] = make_float2(m_c, ssum[0] + ssum[1] + ssum[2] + ssum[3]);

    // ---- pool: P_c[d] = sum_t e_t * h[t][d]  (L2/L3-hot re-read) ----
    const int d4 = tid & 63;
    const int tr = tid >> 6;
    const float* hp = h + (size_t)blockIdx.x * 256 * D_;
    float4 pacc = {0.f, 0.f, 0.f, 0.f};
#pragma unroll
    for (int i = 0; i < 16; ++i) {
        const int r = i * 16 + tr;
        float4 v = *reinterpret_cast<const float4*>(hp + (size_t)r * D_ + d4 * 4);
        const float e = elds[r];
        pacc.x = fmaf(e, v.x, pacc.x);
        pacc.y = fmaf(e, v.y, pacc.y);
        pacc.z = fmaf(e, v.z, pacc.z);
        pacc.w = fmaf(e, v.w, pacc.w);
    }
    redp[tr][d4] = pacc;
    __syncthreads();
    if (tr == 0) {
        float4 o = {0.f, 0.f, 0.f, 0.f};
#pragma unroll
        for (int q = 0; q < 16; ++q) {
            float4 s = redp[q][d4];
            o.x += s.x; o.y += s.y; o.z += s.z; o.w += s.w;
        }
        *reinterpret_cast<float4*>(part + (size_t)blockIdx.x * D_ + d4 * 4) = o;
    }
}

// -----------------------------------------------------------------------------
// Kernel 2: exact flash combine per batch over its 16 chunk-partials.
// out[b][d] = sum_c exp(m_c-M)*P_c[d] / sum_c exp(m_c-M)*s_c,  M = max_c m_c.
// -----------------------------------------------------------------------------
__global__ __launch_bounds__(256) void combine_kernel(
    const float* __restrict__ part, const float2* __restrict__ stats,
    float* __restrict__ out)
{
    const int b = blockIdx.x;
    const int t = threadIdx.x;

    __shared__ float cw[16];

    if (t == 0) {
        float mloc[16], sloc[16];
#pragma unroll
        for (int c = 0; c < 16; ++c) {
            float2 st = stats[b * 16 + c];
            mloc[c] = st.x; sloc[c] = st.y;
        }
        float M = mloc[0];
#pragma unroll
        for (int c = 1; c < 16; ++c) M = fmaxf(M, mloc[c]);
        float S = 0.f;
#pragma unroll
        for (int c = 0; c < 16; ++c) {
            float e = __expf(mloc[c] - M);
            cw[c] = e;
            S = fmaf(e, sloc[c], S);
        }
        const float invS = 1.0f / S;
#pragma unroll
        for (int c = 0; c < 16; ++c) cw[c] *= invS;
    }
    __syncthreads();

    float acc = 0.f;
#pragma unroll
    for (int c = 0; c < 16; ++c)
        acc = fmaf(cw[c], part[((size_t)b * 16 + c) * D_ + t], acc);
    out[b * D_ + t] = acc;
}

extern "C" void kernel_launch(void* const* d_in, const int* in_sizes, int n_in,
                              void* d_out, int out_size, void* d_ws, size_t ws_size,
                              hipStream_t stream) {
    const float* h  = (const float*)d_in[0];
    const float* W  = (const float*)d_in[1];
    const float* bw = (const float*)d_in[2];
    const float* uw = (const float*)d_in[3];
    float* out = (float*)d_out;

    ushort* Wimg  = (ushort*)d_ws;                          // 128 KB
    float*  part  = (float*)(Wimg + (size_t)65536);         // 512*256*4 = 512 KB
    float2* stats = (float2*)(part + (size_t)512 * D_);     // 4 KB

    convert_W_kernel<<<dim3(32), 256, 0, stream>>>(W, Wimg);
    score_pool_kernel<<<dim3((B_ * T_) / 256), 1024, 0, stream>>>(h, Wimg, bw, uw, part, stats);
    combine_kernel<<<dim3(B_), 256, 0, stream>>>(part, stats, out);
}

// Round 11
// 80.408 us; speedup vs baseline: 1.1709x; 1.1709x over previous
//
#include <hip/hip_runtime.h>

#define B_ 32
#define T_ 4096
#define D_ 256
#define A_ 128

typedef __attribute__((ext_vector_type(8))) short bf16x8;
typedef __attribute__((ext_vector_type(4))) float f32x4;
typedef __attribute__((address_space(3))) void lds_void_t;
typedef const __attribute__((address_space(1))) void gbl_void_t;

__device__ __forceinline__ ushort f32_to_bf16_rne(float x) {
    uint u = __float_as_uint(x);
    u = (u + 0x7FFFu + ((u >> 16) & 1u)) >> 16;
    return (ushort)u;
}
__device__ __forceinline__ float bf16_bits_to_f32(ushort b) {
    return __uint_as_float(((uint)b) << 16);
}

// fast tanh: 1 - 2/(e^{2x}+1); exp overflow -> +-1 naturally.
__device__ __forceinline__ float fast_tanh(float x) {
    float t = __expf(2.0f * x);
    float r = __builtin_amdgcn_rcpf(t + 1.0f);
    return fmaf(-2.0f, r, 1.0f);
}

// split 8 f32 -> hi bf16x8 (round-half-up) + lo bf16x8 (exact residual)
__device__ __forceinline__ void split8(float4 a, float4 b, bf16x8& hi8, bf16x8& lo8) {
    float xs[8] = {a.x, a.y, a.z, a.w, b.x, b.y, b.z, b.w};
    union { uint w[4]; bf16x8 v; } H, L;
#pragma unroll
    for (int p = 0; p < 4; ++p) {
        float x0 = xs[2 * p], x1 = xs[2 * p + 1];
        uint r0 = __float_as_uint(x0) + 0x8000u;
        uint r1 = __float_as_uint(x1) + 0x8000u;
        H.w[p] = __builtin_amdgcn_perm(r1, r0, 0x07060302u);
        float rem0 = x0 - __uint_as_float(r0 & 0xFFFF0000u);
        float rem1 = x1 - __uint_as_float(r1 & 0xFFFF0000u);
        L.w[p] = __builtin_amdgcn_perm(__float_as_uint(rem1), __float_as_uint(rem0), 0x07060302u);
    }
    hi8 = H.v;
    lo8 = L.v;
}

// -----------------------------------------------------------------------------
// Kernel 0: pre-swizzled W image, 4 chunks of 32KB (R9's measured-0-conflict
// layout). Byte addr = ph*32768 + p*16384 + r*128 + sp*16, where sp = s^(r&7)
// and the chunk holds bf16 plane p of W[r][ph*64 + s*8 .. +8).
// -----------------------------------------------------------------------------
__global__ __launch_bounds__(256) void convert_W_kernel(
    const float* __restrict__ W, ushort* __restrict__ Wimg)
{
    const int c   = blockIdx.x * 256 + threadIdx.x;   // 16B chunk id, 0..8191
    const int ph  = c >> 11;
    const int p   = (c >> 10) & 1;
    const int r   = (c >> 3) & 127;
    const int sp  = c & 7;
    const int s   = sp ^ (r & 7);
    const float* src = W + (size_t)r * D_ + ph * 64 + s * 8;

    union { ushort us[8]; float4 v; } out;
#pragma unroll
    for (int i = 0; i < 8; ++i) {
        float x = src[i];
        ushort hb = f32_to_bf16_rne(x);
        out.us[i] = p ? f32_to_bf16_rne(x - bf16_bits_to_f32(hb)) : hb;
    }
    *reinterpret_cast<float4*>(Wimg + (size_t)c * 8) = out.v;
}

// -----------------------------------------------------------------------------
// Kernel 1 (fused): score (split-bf16 MFMA) + flash-local pool.
// Full 128KB W image staged ONCE per block via global_load_lds (linear copy,
// swizzle pre-folded in source). ONE __syncthreads; K-loop is barrier-free
// with a rolling depth-4 h prefetch (in-order vmcnt consumption keeps younger
// prefetches in flight - no asm, no pins). Block = 8 waves x 16 rows = 128
// rows = one flash chunk; grid 1024; 1 block/CU; VGPR budget 256 (512,2).
// Pool re-reads the block's own 128 rows (L2/L3-hot, proven R9/R10).
// -----------------------------------------------------------------------------
__global__ __launch_bounds__(512, 2) void score_pool_kernel(
    const float* __restrict__ h, const ushort* __restrict__ Wimg,
    const float* __restrict__ bw, const float* __restrict__ uw,
    float* __restrict__ part, float2* __restrict__ stats)
{
    __shared__ char wlds[131072];       // 4 chunks x [plane][row][swz slot]
    __shared__ float sc[128];
    __shared__ float elds[128];
    __shared__ float ssum[2];
    __shared__ float4 redp[8][64];

    const int tid  = threadIdx.x;
    const int w    = tid >> 6;          // 0..7
    const int lane = tid & 63;
    const int l15  = lane & 15;
    const int l4   = lane >> 4;
    const int rowbase = blockIdx.x * 128 + w * 16;

    // ---- stage the full W image ONCE (16 x global_load_lds / thread) ----
#pragma unroll
    for (int i = 0; i < 16; ++i) {
        __builtin_amdgcn_global_load_lds(
            (gbl_void_t*)((const char*)Wimg + i * 8192 + tid * 16),
            (lds_void_t*)(wlds + i * 8192 + w * 1024), 16, 0, 0);
    }

    const float* hrow = h + (size_t)(rowbase + l15) * D_ + l4 * 8;

    float4 hbuf[8][2];
#define PREF(s)                                                             \
    {                                                                       \
        hbuf[s][0] = *reinterpret_cast<const float4*>(hrow + (s) * 32);     \
        hbuf[s][1] = *reinterpret_cast<const float4*>(hrow + (s) * 32 + 4); \
    }
    PREF(0); PREF(1); PREF(2); PREF(3);

    __syncthreads();   // one-time drain: W resident, h(0..3) landed

    f32x4 acc[8];
#pragma unroll
    for (int j = 0; j < 8; ++j)
#pragma unroll
        for (int r = 0; r < 4; ++r) acc[j][r] = 0.f;

    // ---- barrier-free K-loop ----
#pragma unroll
    for (int kk = 0; kk < 8; ++kk) {
        if (kk < 4) PREF(kk + 4);

        bf16x8 ahi, alo;
        split8(hbuf[kk][0], hbuf[kk][1], ahi, alo);

        const int chunk = kk >> 1;
        const int slot  = (kk & 1) * 4 + l4;
#pragma unroll
        for (int j = 0; j < 8; ++j) {
            const int row = j * 16 + l15;
            const int off = chunk * 32768 + row * 128 + ((slot ^ (row & 7)) << 4);
            bf16x8 wh = *reinterpret_cast<const bf16x8*>(wlds + off);
            bf16x8 wl = *reinterpret_cast<const bf16x8*>(wlds + 16384 + off);
            acc[j] = __builtin_amdgcn_mfma_f32_16x16x32_bf16(ahi, wh, acc[j], 0, 0, 0);
            acc[j] = __builtin_amdgcn_mfma_f32_16x16x32_bf16(alo, wh, acc[j], 0, 0, 0);
            acc[j] = __builtin_amdgcn_mfma_f32_16x16x32_bf16(ahi, wl, acc[j], 0, 0, 0);
        }
    }
#undef PREF

    // ---- scores for the wave's 16 rows ----
    float rsum[4] = {0.f, 0.f, 0.f, 0.f};
#pragma unroll
    for (int j = 0; j < 8; ++j) {
        const float bwv = bw[j * 16 + l15];
        const float uwv = uw[j * 16 + l15];
#pragma unroll
        for (int r = 0; r < 4; ++r)
            rsum[r] = fmaf(fast_tanh(acc[j][r] + bwv), uwv, rsum[r]);
    }
#pragma unroll
    for (int r = 0; r < 4; ++r) {
#pragma unroll
        for (int m = 1; m < 16; m <<= 1)
            rsum[r] += __shfl_xor(rsum[r], m, 64);
    }
    if (l15 == 0) {
#pragma unroll
        for (int r = 0; r < 4; ++r)
            sc[w * 16 + l4 * 4 + r] = rsum[r];
    }
    __syncthreads();

    // ---- flash-local softmax over the block's 128 rows ----
    float m_c = -3.0e38f;
#pragma unroll 16
    for (int t = 0; t < 128; ++t) m_c = fmaxf(m_c, sc[t]);   // LDS broadcast

    if (tid < 128) {
        float e = __expf(sc[tid] - m_c);
        elds[tid] = e;
        float s = e;
#pragma unroll
        for (int msk = 1; msk < 64; msk <<= 1) s += __shfl_xor(s, msk, 64);
        if ((tid & 63) == 0) ssum[tid >> 6] = s;
    }
    __syncthreads();
    if (tid == 0) stats[blockIdx.x] = make_float2(m_c, ssum[0] + ssum[1]);

    // ---- pool: P_c[d] = sum_t e_t * h[t][d]  (L2/L3-hot re-read) ----
    const int d4 = tid & 63;
    const int tr = tid >> 6;            // 0..7
    const float* hp = h + (size_t)blockIdx.x * 128 * D_;
    float4 pacc = {0.f, 0.f, 0.f, 0.f};
#pragma unroll
    for (int i = 0; i < 16; ++i) {
        const int r = i * 8 + tr;
        float4 v = *reinterpret_cast<const float4*>(hp + (size_t)r * D_ + d4 * 4);
        const float e = elds[r];
        pacc.x = fmaf(e, v.x, pacc.x);
        pacc.y = fmaf(e, v.y, pacc.y);
        pacc.z = fmaf(e, v.z, pacc.z);
        pacc.w = fmaf(e, v.w, pacc.w);
    }
    redp[tr][d4] = pacc;
    __syncthreads();
    if (tr == 0) {
        float4 o = {0.f, 0.f, 0.f, 0.f};
#pragma unroll
        for (int q = 0; q < 8; ++q) {
            float4 s = redp[q][d4];
            o.x += s.x; o.y += s.y; o.z += s.z; o.w += s.w;
        }
        *reinterpret_cast<float4*>(part + (size_t)blockIdx.x * D_ + d4 * 4) = o;
    }
}

// -----------------------------------------------------------------------------
// Kernel 2: exact flash combine per batch over its 32 chunk-partials.
// out[b][d] = sum_c exp(m_c-M)*P_c[d] / sum_c exp(m_c-M)*s_c,  M = max_c m_c.
// -----------------------------------------------------------------------------
__global__ __launch_bounds__(256) void combine_kernel(
    const float* __restrict__ part, const float2* __restrict__ stats,
    float* __restrict__ out)
{
    const int b = blockIdx.x;
    const int t = threadIdx.x;

    __shared__ float cw[32];

    if (t < 32) {
        const float2 st = stats[b * 32 + t];
        float M = st.x;
#pragma unroll
        for (int msk = 1; msk < 32; msk <<= 1) M = fmaxf(M, __shfl_xor(M, msk, 64));
        const float em = __expf(st.x - M);
        float S = em * st.y;
#pragma unroll
        for (int msk = 1; msk < 32; msk <<= 1) S += __shfl_xor(S, msk, 64);
        cw[t] = em / S;
    }
    __syncthreads();

    float acc = 0.f;
    const float* pb = part + (size_t)b * 32 * D_ + t;
#pragma unroll 8
    for (int c = 0; c < 32; ++c)
        acc = fmaf(cw[c], pb[(size_t)c * D_], acc);
    out[b * D_ + t] = acc;
}

extern "C" void kernel_launch(void* const* d_in, const int* in_sizes, int n_in,
                              void* d_out, int out_size, void* d_ws, size_t ws_size,
                              hipStream_t stream) {
    const float* h  = (const float*)d_in[0];
    const float* W  = (const float*)d_in[1];
    const float* bw = (const float*)d_in[2];
    const float* uw = (const float*)d_in[3];
    float* out = (float*)d_out;

    ushort* Wimg  = (ushort*)d_ws;                          // 128 KB
    float*  part  = (float*)(Wimg + (size_t)65536);         // 1024*256*4 = 1 MB
    float2* stats = (float2*)(part + (size_t)1024 * D_);    // 8 KB

    convert_W_kernel<<<dim3(32), 256, 0, stream>>>(W, Wimg);
    score_pool_kernel<<<dim3((B_ * T_) / 128), 512, 0, stream>>>(h, Wimg, bw, uw, part, stats);
    combine_kernel<<<dim3(B_), 256, 0, stream>>>(part, stats, out);
}

// Round 12
// 60.256 us; speedup vs baseline: 1.5625x; 1.3345x over previous
//
#include <hip/hip_runtime.h>

#define B_ 32
#define T_ 4096
#define D_ 256
#define A_ 128

typedef __attribute__((ext_vector_type(8))) short bf16x8;
typedef __attribute__((ext_vector_type(4))) float f32x4;
typedef __attribute__((address_space(3))) void lds_void_t;
typedef const __attribute__((address_space(1))) void gbl_void_t;

__device__ __forceinline__ ushort f32_to_bf16_rne(float x) {
    uint u = __float_as_uint(x);
    u = (u + 0x7FFFu + ((u >> 16) & 1u)) >> 16;
    return (ushort)u;
}
__device__ __forceinline__ float bf16_bits_to_f32(ushort b) {
    return __uint_as_float(((uint)b) << 16);
}

__device__ __forceinline__ float fast_tanh(float x) {
    float t = __expf(2.0f * x);
    float r = __builtin_amdgcn_rcpf(t + 1.0f);
    return fmaf(-2.0f, r, 1.0f);
}

// split 8 f32 -> hi bf16x8 (round-half-up) + lo bf16x8 (exact residual)
__device__ __forceinline__ void split8(float4 a, float4 b, bf16x8& hi8, bf16x8& lo8) {
    float xs[8] = {a.x, a.y, a.z, a.w, b.x, b.y, b.z, b.w};
    union { uint w[4]; bf16x8 v; } H, L;
#pragma unroll
    for (int p = 0; p < 4; ++p) {
        float x0 = xs[2 * p], x1 = xs[2 * p + 1];
        uint r0 = __float_as_uint(x0) + 0x8000u;
        uint r1 = __float_as_uint(x1) + 0x8000u;
        H.w[p] = __builtin_amdgcn_perm(r1, r0, 0x07060302u);
        float rem0 = x0 - __uint_as_float(r0 & 0xFFFF0000u);
        float rem1 = x1 - __uint_as_float(r1 & 0xFFFF0000u);
        L.w[p] = __builtin_amdgcn_perm(__float_as_uint(rem1), __float_as_uint(rem0), 0x07060302u);
    }
    hi8 = H.v;
    lo8 = L.v;
}

// -----------------------------------------------------------------------------
// Kernel 0: pre-swizzled W image, 4 chunks of 32KB (R11's verified 0-conflict
// layout). Byte addr = ph*32768 + p*16384 + r*128 + sp*16, sp = s^(r&7).
// -----------------------------------------------------------------------------
__global__ __launch_bounds__(256) void convert_W_kernel(
    const float* __restrict__ W, ushort* __restrict__ Wimg)
{
    const int c   = blockIdx.x * 256 + threadIdx.x;
    const int ph  = c >> 11;
    const int p   = (c >> 10) & 1;
    const int r   = (c >> 3) & 127;
    const int sp  = c & 7;
    const int s   = sp ^ (r & 7);
    const float* src = W + (size_t)r * D_ + ph * 64 + s * 8;

    union { ushort us[8]; float4 v; } out;
#pragma unroll
    for (int i = 0; i < 8; ++i) {
        float x = src[i];
        ushort hb = f32_to_bf16_rne(x);
        out.us[i] = p ? f32_to_bf16_rne(x - bf16_bits_to_f32(hb)) : hb;
    }
    *reinterpret_cast<float4*>(Wimg + (size_t)c * 8) = out.v;
}

// -----------------------------------------------------------------------------
// Kernel 1: fused score + per-wave flash pool. h pipelined THROUGH LDS
// (global_load_lds, double-buffered, counted vmcnt(2), zero in-loop barriers:
// each wave stages & reads only its own 16-row slice). W (128 KB) staged once.
// Block = 8 waves x 16 rows x 4 groups = 512 rows; grid 256 (1 block/CU).
// LDS = 128K W + 32K h = 160 KB exactly. Epilogue fully wave-local.
// -----------------------------------------------------------------------------
__global__ __launch_bounds__(512, 2) void score_pool_kernel(
    const float* __restrict__ h, const ushort* __restrict__ Wimg,
    const float* __restrict__ bw, const float* __restrict__ uw,
    float* __restrict__ part, float2* __restrict__ stats)
{
    __shared__ char smem[163840];
    char* wlds = smem;            // 128 KB W
    char* ht   = smem + 131072;   // 2 x 16 KB h tiles

    const int tid  = threadIdx.x;
    const int w    = tid >> 6;
    const int lane = tid & 63;
    const int l15  = lane & 15;
    const int l4   = lane >> 4;
    const int blk  = blockIdx.x;
    const size_t blkrow = (size_t)blk * 512;

    // preload bias/gate (removes vmem from epilogue)
    float bwv[8], uwv[8];
#pragma unroll
    for (int j = 0; j < 8; ++j) { bwv[j] = bw[j * 16 + l15]; uwv[j] = uw[j * 16 + l15]; }

    // ---- stage W once (linear copy of pre-swizzled image) ----
#pragma unroll
    for (int i = 0; i < 16; ++i)
        __builtin_amdgcn_global_load_lds(
            (gbl_void_t*)((const char*)Wimg + i * 8192 + tid * 16),
            (lds_void_t*)(wlds + i * 8192 + w * 1024), 16, 0, 0);
    asm volatile("s_waitcnt vmcnt(0)" ::: "memory");
    __builtin_amdgcn_s_barrier();
    __builtin_amdgcn_sched_barrier(0);

    // h staging: wave slice = 16 rows x 32 f32 per stage, transposed mapping:
    // inst i, lane l -> row l&15, colslot i*4+(l>>4) (16B of 4 f32).
    const float* hlane = h + (blkrow + (size_t)w * 16 + l15) * D_ + l4 * 4;

#define HSTAGE(s2, buf)                                                         \
    {                                                                           \
        const float* s0_ = hlane + (size_t)((s2) >> 3) * 128 * D_ + ((s2) & 7) * 32; \
        char* d_ = ht + (buf) * 16384 + w * 2048;                               \
        __builtin_amdgcn_global_load_lds((gbl_void_t*)(s0_),      (lds_void_t*)(d_),        16, 0, 0); \
        __builtin_amdgcn_global_load_lds((gbl_void_t*)(s0_ + 16), (lds_void_t*)(d_ + 1024), 16, 0, 0); \
    }

    // per-lane read offsets: slots c=l4*2, l4*2+1 of row l15
    const int reg0 = (l4 >> 1) * 1024;
    const int rd0  = w * 2048 + reg0 + (((l4 * 2)     & 3) * 16 + l15) * 16;
    const int rd1  = w * 2048 + reg0 + (((l4 * 2 + 1) & 3) * 16 + l15) * 16;

    HSTAGE(0, 0);
    HSTAGE(1, 1);

    f32x4 acc[8];
#pragma unroll
    for (int j = 0; j < 8; ++j)
#pragma unroll
        for (int r = 0; r < 4; ++r) acc[j][r] = 0.f;

#pragma unroll
    for (int g = 0; g < 4; ++g) {
#pragma unroll
        for (int kk = 0; kk < 8; ++kk) {
            const int s = g * 8 + kk;
            if (s == 31) { asm volatile("s_waitcnt vmcnt(0)" ::: "memory"); }
            else         { asm volatile("s_waitcnt vmcnt(2)" ::: "memory"); }
            __builtin_amdgcn_sched_barrier(0);

            const int buf = s & 1;
            float4 x0 = *reinterpret_cast<const float4*>(ht + buf * 16384 + rd0);
            float4 x1 = *reinterpret_cast<const float4*>(ht + buf * 16384 + rd1);
            asm volatile("s_waitcnt lgkmcnt(0)" ::: "memory");
            __builtin_amdgcn_sched_barrier(0);
            if (s + 2 < 32) HSTAGE(s + 2, buf);   // safe: reads of this buf retired

            bf16x8 ahi, alo;
            split8(x0, x1, ahi, alo);

            const int chunk = kk >> 1;
            const int slot  = (kk & 1) * 4 + l4;
#pragma unroll
            for (int j = 0; j < 8; ++j) {
                const int row = j * 16 + l15;
                const int off = chunk * 32768 + row * 128 + ((slot ^ (row & 7)) << 4);
                bf16x8 wh = *reinterpret_cast<const bf16x8*>(wlds + off);
                bf16x8 wl = *reinterpret_cast<const bf16x8*>(wlds + 16384 + off);
                acc[j] = __builtin_amdgcn_mfma_f32_16x16x32_bf16(ahi, wh, acc[j], 0, 0, 0);
                acc[j] = __builtin_amdgcn_mfma_f32_16x16x32_bf16(alo, wh, acc[j], 0, 0, 0);
                acc[j] = __builtin_amdgcn_mfma_f32_16x16x32_bf16(ahi, wl, acc[j], 0, 0, 0);
            }
        }

        // ---- wave-local epilogue for group g ----
        float rsum[4] = {0.f, 0.f, 0.f, 0.f};
#pragma unroll
        for (int j = 0; j < 8; ++j)
#pragma unroll
            for (int r = 0; r < 4; ++r) {
                rsum[r] = fmaf(fast_tanh(acc[j][r] + bwv[j]), uwv[j], rsum[r]);
                acc[j][r] = 0.f;   // reset for next group
            }
#pragma unroll
        for (int r = 0; r < 4; ++r) {
#pragma unroll
            for (int m = 1; m < 16; m <<= 1)
                rsum[r] += __shfl_xor(rsum[r], m, 64);
        }
        // gather all 16 scores of this wave's rows
        float sc16[16];
#pragma unroll
        for (int rr = 0; rr < 16; ++rr)
            sc16[rr] = __shfl(rsum[rr & 3], (rr >> 2) << 4, 64);

        float m_w = sc16[0];
#pragma unroll
        for (int rr = 1; rr < 16; ++rr) m_w = fmaxf(m_w, sc16[rr]);
        float e16[16], s_w = 0.f;
#pragma unroll
        for (int rr = 0; rr < 16; ++rr) { e16[rr] = __expf(sc16[rr] - m_w); s_w += e16[rr]; }

        // pool this wave's 16 rows (L2-hot: just streamed through LDS)
        const float* hg = h + (blkrow + (size_t)g * 128 + w * 16) * D_ + lane * 4;
        float4 pacc = {0.f, 0.f, 0.f, 0.f};
#pragma unroll
        for (int r = 0; r < 16; ++r) {
            float4 v = *reinterpret_cast<const float4*>(hg + (size_t)r * D_);
            pacc.x = fmaf(e16[r], v.x, pacc.x);
            pacc.y = fmaf(e16[r], v.y, pacc.y);
            pacc.z = fmaf(e16[r], v.z, pacc.z);
            pacc.w = fmaf(e16[r], v.w, pacc.w);
        }
        const int chunkid = blk * 32 + g * 8 + w;
        *reinterpret_cast<float4*>(part + (size_t)chunkid * D_ + lane * 4) = pacc;
        if (lane == 0) stats[chunkid] = make_float2(m_w, s_w);

        asm volatile("s_waitcnt vmcnt(0)" ::: "memory");   // resync (tiles already landed)
        __builtin_amdgcn_sched_barrier(0);
    }
#undef HSTAGE
}

// -----------------------------------------------------------------------------
// Kernel 2: per-batch flash combine over 256 wave-chunks (R5-proven structure).
// out[b][d] = sum_c exp(m_c-M)*P_c[d] / sum_c exp(m_c-M)*s_c.
// -----------------------------------------------------------------------------
__global__ __launch_bounds__(256) void combine_kernel(
    const float* __restrict__ part, const float2* __restrict__ stats,
    float* __restrict__ out)
{
    const int b = blockIdx.x;
    const int t = threadIdx.x;

    __shared__ float red[256];
    __shared__ float cw[256];

    const float2 stt = stats[b * 256 + t];
    red[t] = stt.x;
    __syncthreads();
    for (int s = 128; s > 0; s >>= 1) {
        if (t < s) red[t] = fmaxf(red[t], red[t + s]);
        __syncthreads();
    }
    const float M = red[0];
    __syncthreads();
    const float em = __expf(stt.x - M);
    red[t] = em * stt.y;
    __syncthreads();
    for (int s = 128; s > 0; s >>= 1) {
        if (t < s) red[t] += red[t + s];
        __syncthreads();
    }
    const float invS = 1.0f / red[0];
    cw[t] = em * invS;
    __syncthreads();

    float acc = 0.f;
    const float* pb = part + (size_t)b * 256 * D_ + t;
#pragma unroll 8
    for (int c = 0; c < 256; ++c)
        acc = fmaf(cw[c], pb[(size_t)c * D_], acc);
    out[b * D_ + t] = acc;
}

extern "C" void kernel_launch(void* const* d_in, const int* in_sizes, int n_in,
                              void* d_out, int out_size, void* d_ws, size_t ws_size,
                              hipStream_t stream) {
    const float* h  = (const float*)d_in[0];
    const float* W  = (const float*)d_in[1];
    const float* bw = (const float*)d_in[2];
    const float* uw = (const float*)d_in[3];
    float* out = (float*)d_out;

    ushort* Wimg  = (ushort*)d_ws;                          // 128 KB
    float*  part  = (float*)(Wimg + (size_t)65536);         // 8192*256*4 = 8 MB
    float2* stats = (float2*)(part + (size_t)8192 * D_);    // 64 KB

    convert_W_kernel<<<dim3(32), 256, 0, stream>>>(W, Wimg);
    score_pool_kernel<<<dim3(256), 512, 0, stream>>>(h, Wimg, bw, uw, part, stats);
    combine_kernel<<<dim3(B_), 256, 0, stream>>>(part, stats, out);
}

// Round 13
// 50.406 us; speedup vs baseline: 1.8678x; 1.1954x over previous
//
#include <hip/hip_runtime.h>

#define B_ 32
#define T_ 4096
#define D_ 256
#define A_ 128

typedef __attribute__((ext_vector_type(8))) short bf16x8;
typedef __attribute__((ext_vector_type(4))) float f32x4;
typedef __attribute__((address_space(3))) void lds_void_t;
typedef const __attribute__((address_space(1))) void gbl_void_t;

__device__ __forceinline__ ushort f32_to_bf16_rne(float x) {
    uint u = __float_as_uint(x);
    u = (u + 0x7FFFu + ((u >> 16) & 1u)) >> 16;
    return (ushort)u;
}
__device__ __forceinline__ float bf16_bits_to_f32(ushort b) {
    return __uint_as_float(((uint)b) << 16);
}

__device__ __forceinline__ float fast_tanh(float x) {
    float t = __expf(2.0f * x);
    float r = __builtin_amdgcn_rcpf(t + 1.0f);
    return fmaf(-2.0f, r, 1.0f);
}

// split 8 f32 -> hi bf16x8 (round-half-up) + lo bf16x8 (exact residual)
__device__ __forceinline__ void split8(float4 a, float4 b, bf16x8& hi8, bf16x8& lo8) {
    float xs[8] = {a.x, a.y, a.z, a.w, b.x, b.y, b.z, b.w};
    union { uint w[4]; bf16x8 v; } H, L;
#pragma unroll
    for (int p = 0; p < 4; ++p) {
        float x0 = xs[2 * p], x1 = xs[2 * p + 1];
        uint r0 = __float_as_uint(x0) + 0x8000u;
        uint r1 = __float_as_uint(x1) + 0x8000u;
        H.w[p] = __builtin_amdgcn_perm(r1, r0, 0x07060302u);
        float rem0 = x0 - __uint_as_float(r0 & 0xFFFF0000u);
        float rem1 = x1 - __uint_as_float(r1 & 0xFFFF0000u);
        L.w[p] = __builtin_amdgcn_perm(__float_as_uint(rem1), __float_as_uint(rem0), 0x07060302u);
    }
    hi8 = H.v;
    lo8 = L.v;
}

// -----------------------------------------------------------------------------
// Kernel 0: pre-swizzled W image, 4 chunks of 32KB (verified 0-conflict layout).
// Byte addr = ph*32768 + p*16384 + r*128 + sp*16, sp = s^(r&7).
// -----------------------------------------------------------------------------
__global__ __launch_bounds__(256) void convert_W_kernel(
    const float* __restrict__ W, ushort* __restrict__ Wimg)
{
    const int c   = blockIdx.x * 256 + threadIdx.x;
    const int ph  = c >> 11;
    const int p   = (c >> 10) & 1;
    const int r   = (c >> 3) & 127;
    const int sp  = c & 7;
    const int s   = sp ^ (r & 7);
    const float* src = W + (size_t)r * D_ + ph * 64 + s * 8;

    union { ushort us[8]; float4 v; } out;
#pragma unroll
    for (int i = 0; i < 8; ++i) {
        float x = src[i];
        ushort hb = f32_to_bf16_rne(x);
        out.us[i] = p ? f32_to_bf16_rne(x - bf16_bits_to_f32(hb)) : hb;
    }
    *reinterpret_cast<float4*>(Wimg + (size_t)c * 8) = out.v;
}

// -----------------------------------------------------------------------------
// Kernel 1: fused score + per-wave flash pool + BLOCK flash merge.
// K-loop identical to R12 (proven): h pipelined through LDS via global_load_lds,
// double-buffered, counted vmcnt(2), zero in-loop barriers; W (128KB) staged
// once. New: group partials/stats held in registers, merged across the block's
// 32 chunks in LDS at the end -> ONE partial (256 f32) per block.
// Block = 8 waves x 16 rows x 4 groups = 512 rows; grid 256 (1 block/CU).
// -----------------------------------------------------------------------------
__global__ __launch_bounds__(512, 2) void score_pool_kernel(
    const float* __restrict__ h, const ushort* __restrict__ Wimg,
    const float* __restrict__ bw, const float* __restrict__ uw,
    float* __restrict__ part, float2* __restrict__ stats)
{
    __shared__ char smem[163840];
    char* wlds = smem;            // 128 KB W
    char* ht   = smem + 131072;   // 2 x 16 KB h tiles

    const int tid  = threadIdx.x;
    const int w    = tid >> 6;
    const int lane = tid & 63;
    const int l15  = lane & 15;
    const int l4   = lane >> 4;
    const int blk  = blockIdx.x;
    const size_t blkrow = (size_t)blk * 512;

    // preload bias/gate (removes vmem from epilogue)
    float bwv[8], uwv[8];
#pragma unroll
    for (int j = 0; j < 8; ++j) { bwv[j] = bw[j * 16 + l15]; uwv[j] = uw[j * 16 + l15]; }
    __builtin_amdgcn_sched_barrier(0);

    // h staging geometry (R12): wave slice = 16 rows x 32 f32 per stage.
    const float* hlane = h + (blkrow + (size_t)w * 16 + l15) * D_ + l4 * 4;

#define HSTAGE(s2, buf)                                                         \
    {                                                                           \
        const float* s0_ = hlane + (size_t)((s2) >> 3) * 128 * D_ + ((s2) & 7) * 32; \
        char* d_ = ht + (buf) * 16384 + w * 2048;                               \
        __builtin_amdgcn_global_load_lds((gbl_void_t*)(s0_),      (lds_void_t*)(d_),        16, 0, 0); \
        __builtin_amdgcn_global_load_lds((gbl_void_t*)(s0_ + 16), (lds_void_t*)(d_ + 1024), 16, 0, 0); \
    }

    // ---- stage W once; h0/h1 queued BEHIND it; wait W (h stays in flight) ----
#pragma unroll
    for (int i = 0; i < 16; ++i)
        __builtin_amdgcn_global_load_lds(
            (gbl_void_t*)((const char*)Wimg + i * 8192 + tid * 16),
            (lds_void_t*)(wlds + i * 8192 + w * 1024), 16, 0, 0);
    HSTAGE(0, 0);
    HSTAGE(1, 1);
    asm volatile("s_waitcnt vmcnt(4)" ::: "memory");   // W landed; h0,h1 in flight
    __builtin_amdgcn_sched_barrier(0);
    __builtin_amdgcn_s_barrier();
    __builtin_amdgcn_sched_barrier(0);

    // per-lane read offsets: slots c=l4*2, l4*2+1 of row l15
    const int reg0 = (l4 >> 1) * 1024;
    const int rd0  = w * 2048 + reg0 + (((l4 * 2)     & 3) * 16 + l15) * 16;
    const int rd1  = w * 2048 + reg0 + (((l4 * 2 + 1) & 3) * 16 + l15) * 16;

    f32x4 acc[8];
#pragma unroll
    for (int j = 0; j < 8; ++j)
#pragma unroll
        for (int r = 0; r < 4; ++r) acc[j][r] = 0.f;

    float4 pacc[4];
    float  m_arr[4], s_arr[4];

#pragma unroll
    for (int g = 0; g < 4; ++g) {
#pragma unroll
        for (int kk = 0; kk < 8; ++kk) {
            const int s = g * 8 + kk;
            if (s == 31) { asm volatile("s_waitcnt vmcnt(0)" ::: "memory"); }
            else         { asm volatile("s_waitcnt vmcnt(2)" ::: "memory"); }
            __builtin_amdgcn_sched_barrier(0);

            const int buf = s & 1;
            float4 x0 = *reinterpret_cast<const float4*>(ht + buf * 16384 + rd0);
            float4 x1 = *reinterpret_cast<const float4*>(ht + buf * 16384 + rd1);
            asm volatile("s_waitcnt lgkmcnt(0)" ::: "memory");
            __builtin_amdgcn_sched_barrier(0);
            if (s + 2 < 32) HSTAGE(s + 2, buf);   // safe: reads of this buf retired

            bf16x8 ahi, alo;
            split8(x0, x1, ahi, alo);

            const int chunk = kk >> 1;
            const int slot  = (kk & 1) * 4 + l4;
#pragma unroll
            for (int j = 0; j < 8; ++j) {
                const int row = j * 16 + l15;
                const int off = chunk * 32768 + row * 128 + ((slot ^ (row & 7)) << 4);
                bf16x8 wh = *reinterpret_cast<const bf16x8*>(wlds + off);
                bf16x8 wl = *reinterpret_cast<const bf16x8*>(wlds + 16384 + off);
                acc[j] = __builtin_amdgcn_mfma_f32_16x16x32_bf16(ahi, wh, acc[j], 0, 0, 0);
                acc[j] = __builtin_amdgcn_mfma_f32_16x16x32_bf16(alo, wh, acc[j], 0, 0, 0);
                acc[j] = __builtin_amdgcn_mfma_f32_16x16x32_bf16(ahi, wl, acc[j], 0, 0, 0);
            }
        }

        // ---- wave-local epilogue for group g (results stay in registers) ----
        float rsum[4] = {0.f, 0.f, 0.f, 0.f};
#pragma unroll
        for (int j = 0; j < 8; ++j)
#pragma unroll
            for (int r = 0; r < 4; ++r) {
                rsum[r] = fmaf(fast_tanh(acc[j][r] + bwv[j]), uwv[j], rsum[r]);
                acc[j][r] = 0.f;   // reset for next group
            }
#pragma unroll
        for (int r = 0; r < 4; ++r) {
#pragma unroll
            for (int m = 1; m < 16; m <<= 1)
                rsum[r] += __shfl_xor(rsum[r], m, 64);
        }
        float sc16[16];
#pragma unroll
        for (int rr = 0; rr < 16; ++rr)
            sc16[rr] = __shfl(rsum[rr & 3], (rr >> 2) << 4, 64);

        float m_w = sc16[0];
#pragma unroll
        for (int rr = 1; rr < 16; ++rr) m_w = fmaxf(m_w, sc16[rr]);
        float e16[16], s_w = 0.f;
#pragma unroll
        for (int rr = 0; rr < 16; ++rr) { e16[rr] = __expf(sc16[rr] - m_w); s_w += e16[rr]; }

        // pool this wave's 16 rows (L2-hot: just streamed through LDS)
        const float* hg = h + (blkrow + (size_t)g * 128 + w * 16) * D_ + lane * 4;
        float4 pg = {0.f, 0.f, 0.f, 0.f};
#pragma unroll
        for (int r = 0; r < 16; ++r) {
            float4 v = *reinterpret_cast<const float4*>(hg + (size_t)r * D_);
            pg.x = fmaf(e16[r], v.x, pg.x);
            pg.y = fmaf(e16[r], v.y, pg.y);
            pg.z = fmaf(e16[r], v.z, pg.z);
            pg.w = fmaf(e16[r], v.w, pg.w);
        }
        pacc[g]  = pg;
        m_arr[g] = m_w;
        s_arr[g] = s_w;

        asm volatile("s_waitcnt vmcnt(0)" ::: "memory");   // resync ledger
        __builtin_amdgcn_sched_barrier(0);
    }
#undef HSTAGE

    // ---- block flash merge over 32 chunks (reuse dead W/h LDS) ----
    float2* mst = (float2*)wlds;
    float*  Pl  = (float*)ht;
    __syncthreads();   // all waves done with W reads / h tiles
#pragma unroll
    for (int g = 0; g < 4; ++g) {
        const int cid = g * 8 + w;
        *reinterpret_cast<float4*>(Pl + cid * 256 + lane * 4) = pacc[g];
        if (lane == 0) mst[cid] = make_float2(m_arr[g], s_arr[g]);
    }
    __syncthreads();
    if (tid < 256) {
        float M = -3.0e38f;
#pragma unroll
        for (int c = 0; c < 32; ++c) M = fmaxf(M, mst[c].x);
        float wc[32], S = 0.f;
#pragma unroll
        for (int c = 0; c < 32; ++c) {
            wc[c] = __expf(mst[c].x - M);
            S = fmaf(wc[c], mst[c].y, S);
        }
        float p = 0.f;
#pragma unroll
        for (int c = 0; c < 32; ++c) p = fmaf(wc[c], Pl[c * 256 + tid], p);
        part[(size_t)blk * 256 + tid] = p;
        if (tid == 0) stats[blk] = make_float2(M, S);
    }
}

// -----------------------------------------------------------------------------
// Kernel 2: per-batch flash combine over 8 block-partials. One block per batch.
// out[b][d] = sum_c exp(M_c-Mg)*P_c[d] / sum_c exp(M_c-Mg)*S_c.
// -----------------------------------------------------------------------------
__global__ __launch_bounds__(256) void combine_kernel(
    const float* __restrict__ part, const float2* __restrict__ stats,
    float* __restrict__ out)
{
    const int b = blockIdx.x;
    const int t = threadIdx.x;

    float m8[8], s8[8];
    float Mg = -3.0e38f;
#pragma unroll
    for (int c = 0; c < 8; ++c) {
        float2 st = stats[b * 8 + c];
        m8[c] = st.x; s8[c] = st.y;
        Mg = fmaxf(Mg, st.x);
    }
    float wc[8], S = 0.f;
#pragma unroll
    for (int c = 0; c < 8; ++c) {
        wc[c] = __expf(m8[c] - Mg);
        S = fmaf(wc[c], s8[c], S);
    }
    const float invS = 1.0f / S;

    float acc = 0.f;
#pragma unroll
    for (int c = 0; c < 8; ++c)
        acc = fmaf(wc[c], part[((size_t)b * 8 + c) * D_ + t], acc);
    out[b * D_ + t] = acc * invS;
}

extern "C" void kernel_launch(void* const* d_in, const int* in_sizes, int n_in,
                              void* d_out, int out_size, void* d_ws, size_t ws_size,
                              hipStream_t stream) {
    const float* h  = (const float*)d_in[0];
    const float* W  = (const float*)d_in[1];
    const float* bw = (const float*)d_in[2];
    const float* uw = (const float*)d_in[3];
    float* out = (float*)d_out;

    ushort* Wimg  = (ushort*)d_ws;                          // 128 KB
    float*  part  = (float*)(Wimg + (size_t)65536);         // 256*256*4 = 256 KB
    float2* stats = (float2*)(part + (size_t)256 * D_);     // 2 KB

    convert_W_kernel<<<dim3(32), 256, 0, stream>>>(W, Wimg);
    score_pool_kernel<<<dim3(256), 512, 0, stream>>>(h, Wimg, bw, uw, part, stats);
    combine_kernel<<<dim3(B_), 256, 0, stream>>>(part, stats, out);
}